// Round 1
// baseline (180.718 us; speedup 1.0000x reference)
//
#include <hip/hip_runtime.h>

// DynamicConv1D: out[b,t,f] = sum_{k,d} xp[b,t+k,d] * kernels[b,t,k,f]
// Factorizes: out[b,t,f] = sum_k S[b,t+k-1] * kernels[b,t,k,f],
// where S[b,u] = sum_d x[b,u,d], S out-of-range = 0.
// B=8, T=2048, D=512, K=3, F=512. All fp32. Memory-bound (~160 MiB traffic).
//
// Fused single-kernel version: each block owns TCHUNK=16 consecutive t-rows,
// computes the 18 row sums it needs into LDS (12.5% redundant x-reads,
// +4 MiB), then does the 3-tap combine. Removes the second dispatch, the
// inter-kernel dependency gap, and the S[] global round-trip.

#define B_ 8
#define T_ 2048
#define D_ 512
#define F_ 512
#define TCHUNK 16
#define CHUNKS_PER_B (T_ / TCHUNK)

__global__ __launch_bounds__(256) void fused_conv(
    const float* __restrict__ x, const float* __restrict__ kern,
    float* __restrict__ out) {
    __shared__ float Ssh[TCHUNK + 2];

    const int chunk = blockIdx.x;                 // 0 .. B*T/TCHUNK - 1
    const int b  = chunk / CHUNKS_PER_B;
    const int t0 = (chunk - b * CHUNKS_PER_B) * TCHUNK;
    const int wave = threadIdx.x >> 6;
    const int lane = threadIdx.x & 63;

    // ---- Phase 1: row sums S[t0-1 .. t0+TCHUNK] into LDS (18 rows, 4 waves)
    // One wave per row; D/4 = 128 float4, 64 lanes -> 2 float4 each.
    for (int r = wave; r < TCHUNK + 2; r += 4) {
        const int t = t0 - 1 + r;
        float s = 0.0f;
        if (t >= 0 && t < T_) {
            const float4* xr = (const float4*)(x + ((size_t)b * T_ + t) * D_);
            float4 a = xr[lane];
            float4 c = xr[lane + 64];
            s = (a.x + a.y) + (a.z + a.w) + (c.x + c.y) + (c.z + c.w);
            #pragma unroll
            for (int off = 32; off > 0; off >>= 1)
                s += __shfl_down(s, off, 64);
        }
        if (lane == 0) Ssh[r] = s;   // Ssh[r] = S[t0 - 1 + r], 0 if OOB
    }
    __syncthreads();

    // ---- Phase 2: 3-tap combine. 256 threads -> 2 rows per pass
    // (128 float4 = F per row). Ssh index is wave-uniform -> LDS broadcast.
    const int fi   = threadIdx.x & 127;   // float4 index within F
    const int rsub = threadIdx.x >> 7;    // 0 or 1
    #pragma unroll
    for (int r = rsub; r < TCHUNK; r += 2) {
        const size_t bt = (size_t)b * T_ + t0 + r;
        const float4* kr = (const float4*)(kern + bt * (size_t)(3 * F_));
        const float s0 = Ssh[r];          // tap k=0 uses S[t-1]
        const float s1 = Ssh[r + 1];      // tap k=1 uses S[t]
        const float s2 = Ssh[r + 2];      // tap k=2 uses S[t+1]
        float4 k0 = kr[fi];
        float4 k1 = kr[fi + (F_ / 4)];
        float4 k2 = kr[fi + 2 * (F_ / 4)];
        float4 o;
        o.x = s0 * k0.x + s1 * k1.x + s2 * k2.x;
        o.y = s0 * k0.y + s1 * k1.y + s2 * k2.y;
        o.z = s0 * k0.z + s1 * k1.z + s2 * k2.z;
        o.w = s0 * k0.w + s1 * k1.w + s2 * k2.w;
        ((float4*)(out + bt * F_))[fi] = o;
    }
}

extern "C" void kernel_launch(void* const* d_in, const int* in_sizes, int n_in,
                              void* d_out, int out_size, void* d_ws, size_t ws_size,
                              hipStream_t stream) {
    const float* x    = (const float*)d_in[0];   // [B, T, D]
    const float* kern = (const float*)d_in[1];   // [B, T, K, F]
    float* out = (float*)d_out;                  // [B, T, F]
    (void)d_ws; (void)ws_size;

    fused_conv<<<(B_ * T_) / TCHUNK, 256, 0, stream>>>(x, kern, out);
}

// Round 3
// 180.627 us; speedup vs baseline: 1.0005x; 1.0005x over previous
//
#include <hip/hip_runtime.h>

// DynamicConv1D: out[b,t,f] = sum_{k,d} xp[b,t+k,d] * kernels[b,t,k,f]
// Factorizes: out[b,t,f] = sum_k S[b,t+k-1] * kernels[b,t,k,f],
// where S[b,u] = sum_d x[b,u,d], S out-of-range = 0.
// B=8, T=2048, D=512, K=3, F=512. All fp32. ~160 MiB logical traffic.
//
// v2 (resubmit after infra failure): latency-oriented restructure.
// TCHUNK=8 (grid 2048 = 8 blocks/CU), and each thread PRELOADS all its
// kern float4s into registers BEFORE the row-sum barrier — the kern loads
// don't depend on S, so ~12 independent 16B loads stay in flight across
// the barrier (MLP), instead of being serialized behind phase 1's
// x-load + shfl chain.

#define B_ 8
#define T_ 2048
#define D_ 512
#define F_ 512
#define TCHUNK 8
#define CHUNKS_PER_B (T_ / TCHUNK)   // 256
#define NPASS (TCHUNK / 2)           // 4 rows per thread

__global__ __launch_bounds__(256) void fused_conv(
    const float* __restrict__ x, const float* __restrict__ kern,
    float* __restrict__ out) {
    __shared__ float Ssh[TCHUNK + 2];

    const int chunk = blockIdx.x;                 // 0 .. B*T/TCHUNK - 1
    const int b  = chunk >> 8;                    // / CHUNKS_PER_B
    const int t0 = (chunk & (CHUNKS_PER_B - 1)) * TCHUNK;
    const int wave = threadIdx.x >> 6;
    const int lane = threadIdx.x & 63;
    const int fi   = threadIdx.x & 127;           // float4 index within F
    const int rsub = threadIdx.x >> 7;            // 0 or 1

    const size_t bt0 = (size_t)b * T_ + t0;

    // ---- Preload kern for this thread's NPASS rows (independent of S).
    // Issued first so these ~12 loads overlap phase 1 and the barrier.
    float4 kk[NPASS][3];
    #pragma unroll
    for (int p = 0; p < NPASS; ++p) {
        const int r = rsub + 2 * p;
        const float4* kr = (const float4*)(kern + (bt0 + r) * (size_t)(3 * F_));
        kk[p][0] = kr[fi];
        kk[p][1] = kr[fi + (F_ / 4)];
        kk[p][2] = kr[fi + 2 * (F_ / 4)];
    }

    // ---- Phase 1: row sums S[t0-1 .. t0+TCHUNK] into LDS (10 rows, 4 waves)
    for (int r = wave; r < TCHUNK + 2; r += 4) {
        const int t = t0 - 1 + r;
        float s = 0.0f;
        if (t >= 0 && t < T_) {
            const float4* xr = (const float4*)(x + ((size_t)b * T_ + t) * D_);
            float4 a = xr[lane];
            float4 c = xr[lane + 64];
            s = (a.x + a.y) + (a.z + a.w) + (c.x + c.y) + (c.z + c.w);
            #pragma unroll
            for (int off = 32; off > 0; off >>= 1)
                s += __shfl_down(s, off, 64);
        }
        if (lane == 0) Ssh[r] = s;   // Ssh[r] = S[t0 - 1 + r], 0 if OOB
    }
    __syncthreads();

    // ---- Phase 2: 3-tap combine from registers; Ssh reads are wave-uniform
    // LDS broadcasts.
    #pragma unroll
    for (int p = 0; p < NPASS; ++p) {
        const int r = rsub + 2 * p;
        const float s0 = Ssh[r];          // tap k=0 uses S[t-1]
        const float s1 = Ssh[r + 1];      // tap k=1 uses S[t]
        const float s2 = Ssh[r + 2];      // tap k=2 uses S[t+1]
        float4 o;
        o.x = s0 * kk[p][0].x + s1 * kk[p][1].x + s2 * kk[p][2].x;
        o.y = s0 * kk[p][0].y + s1 * kk[p][1].y + s2 * kk[p][2].y;
        o.z = s0 * kk[p][0].z + s1 * kk[p][1].z + s2 * kk[p][2].z;
        o.w = s0 * kk[p][0].w + s1 * kk[p][1].w + s2 * kk[p][2].w;
        ((float4*)(out + (bt0 + r) * F_))[fi] = o;
    }
}

extern "C" void kernel_launch(void* const* d_in, const int* in_sizes, int n_in,
                              void* d_out, int out_size, void* d_ws, size_t ws_size,
                              hipStream_t stream) {
    const float* x    = (const float*)d_in[0];   // [B, T, D]
    const float* kern = (const float*)d_in[1];   // [B, T, K, F]
    float* out = (float*)d_out;                  // [B, T, F]
    (void)d_ws; (void)ws_size;

    fused_conv<<<(B_ * T_) / TCHUNK, 256, 0, stream>>>(x, kern, out);
}

// Round 4
// 180.059 us; speedup vs baseline: 1.0037x; 1.0032x over previous
//
#include <hip/hip_runtime.h>

// DynamicConv1D: out[b,t,f] = sum_{k,d} xp[b,t+k,d] * kernels[b,t,k,f]
// Factorizes: out[b,t,f] = sum_k S[b,t+k-1] * kernels[b,t,k,f],
// where S[b,u] = sum_d x[b,u,d], S out-of-range = 0.
// B=8, T=2048, D=512, K=3, F=512. fp32. 160 MiB logical traffic.
//
// v3: two dispatches again, but the hot conv kernel is a pure barrier-free
// stream with 12 independent 16B loads in flight per thread (4 output rows
// x 3 taps). Round-3 evidence: VGPR=40 proved the compiler sank preloads
// past the __syncthreads -> MLP starvation (1.7 TB/s, 27% of ceiling).
// No barrier => loads can all be issued before first use.

#define B_ 8
#define T_ 2048
#define D_ 512
#define F_ 512
#define ROWS_PER_BLOCK 8
#define NP (ROWS_PER_BLOCK / 2)      // 4 rows per thread

// Kernel 1: row sums. One wave (64 lanes) per (b,t) row; 4 waves per block.
__global__ __launch_bounds__(256) void rowsum_kernel(
    const float* __restrict__ x, float* __restrict__ S) {
    const int row  = blockIdx.x * 4 + (threadIdx.x >> 6);   // 0 .. B*T-1
    const int lane = threadIdx.x & 63;
    const float4* xr = (const float4*)(x + (size_t)row * D_);
    float4 a = xr[lane];
    float4 b = xr[lane + 64];
    float s = (a.x + a.y) + (a.z + a.w) + (b.x + b.y) + (b.z + b.w);
    #pragma unroll
    for (int off = 32; off > 0; off >>= 1)
        s += __shfl_down(s, off, 64);
    if (lane == 0) S[row] = s;
}

// Kernel 2: 3-tap combine, barrier-free. Each block owns 8 consecutive t
// rows; each thread owns 4 of them at one float4 f-slot -> 12 independent
// kern loads issued up front. S taps are wave-uniform (rsub is uniform
// across each wave) -> scalar loads, L2-resident.
__global__ __launch_bounds__(256, 4) void conv_kernel(
    const float* __restrict__ kern, const float* __restrict__ S,
    float* __restrict__ out) {
    const int chunk = blockIdx.x;                  // 0 .. B*T/8 - 1
    const int b  = chunk >> 8;                     // T/8 = 256 chunks per b
    const int t0 = (chunk & 255) * ROWS_PER_BLOCK;
    const int fi   = threadIdx.x & 127;            // float4 slot in F
    const int rsub = threadIdx.x >> 7;             // 0 or 1 (wave-uniform)
    const size_t bt0 = (size_t)b * T_ + t0;

    // ---- Issue all 12 kern loads (independent, coalesced).
    float4 kk[NP][3];
    #pragma unroll
    for (int p = 0; p < NP; ++p) {
        const int r = rsub + 2 * p;
        const float4* kr = (const float4*)(kern + (bt0 + r) * (size_t)(3 * F_));
        kk[p][0] = kr[fi];
        kk[p][1] = kr[fi + (F_ / 4)];
        kk[p][2] = kr[fi + 2 * (F_ / 4)];
    }

    // ---- S taps (wave-uniform addresses; boundary rows get 0).
    float sv[NP][3];
    #pragma unroll
    for (int p = 0; p < NP; ++p) {
        const int r = rsub + 2 * p;
        const int t = t0 + r;
        sv[p][0] = (t > 0)      ? S[bt0 + r - 1] : 0.0f;
        sv[p][1] = S[bt0 + r];
        sv[p][2] = (t < T_ - 1) ? S[bt0 + r + 1] : 0.0f;
    }

    // ---- Combine + store.
    #pragma unroll
    for (int p = 0; p < NP; ++p) {
        const int r = rsub + 2 * p;
        float4 o;
        o.x = sv[p][0] * kk[p][0].x + sv[p][1] * kk[p][1].x + sv[p][2] * kk[p][2].x;
        o.y = sv[p][0] * kk[p][0].y + sv[p][1] * kk[p][1].y + sv[p][2] * kk[p][2].y;
        o.z = sv[p][0] * kk[p][0].z + sv[p][1] * kk[p][1].z + sv[p][2] * kk[p][2].z;
        o.w = sv[p][0] * kk[p][0].w + sv[p][1] * kk[p][1].w + sv[p][2] * kk[p][2].w;
        ((float4*)(out + (bt0 + r) * F_))[fi] = o;
    }
}

extern "C" void kernel_launch(void* const* d_in, const int* in_sizes, int n_in,
                              void* d_out, int out_size, void* d_ws, size_t ws_size,
                              hipStream_t stream) {
    const float* x    = (const float*)d_in[0];   // [B, T, D]
    const float* kern = (const float*)d_in[1];   // [B, T, K, F]
    float* out = (float*)d_out;                  // [B, T, F]
    float* S   = (float*)d_ws;                   // [B*T] row sums (64 KiB)

    const int rows = B_ * T_;                    // 16384
    rowsum_kernel<<<rows / 4, 256, 0, stream>>>(x, S);
    conv_kernel<<<rows / ROWS_PER_BLOCK, 256, 0, stream>>>(kern, S, out);
}

// Round 5
// 178.533 us; speedup vs baseline: 1.0122x; 1.0086x over previous
//
#include <hip/hip_runtime.h>

// DynamicConv1D: out[b,t,f] = sum_{k,d} xp[b,t+k,d] * kernels[b,t,k,f]
// Factorizes: out[b,t,f] = sum_k S[b,t+k-1] * kernels[b,t,k,f],
// where S[b,u] = sum_d x[b,u,d], S out-of-range = 0.
// B=8, T=2048, D=512, K=3, F=512. fp32.
//
// v4: single wave-autonomous kernel. One wave per 2 consecutive t-rows:
//  - loads 4 x-rows (8 float4/lane) + 12 kern float4/lane up front
//    (20 independent 16B loads in flight, no barrier anywhere to sink past)
//  - butterfly shfl_xor row-sum reduction in-wave (all lanes get the sum)
//  - 3-tap FMA + coalesced float4 stores.
// No LDS, no __syncthreads, no second dispatch. Adjacent waves re-read
// 2 of 4 x-rows (x traffic 2x logical = 64 MiB, mostly L2/L3-absorbed).

#define B_ 8
#define T_ 2048
#define D_ 512
#define F_ 512

__global__ __launch_bounds__(256, 4) void fused_wave(
    const float* __restrict__ x, const float* __restrict__ kern,
    float* __restrict__ out) {
    const int wid  = (blockIdx.x << 2) + (threadIdx.x >> 6); // 0 .. 8191
    const int lane = threadIdx.x & 63;
    const int b  = wid >> 10;             // T/2 = 1024 wave-groups per b
    const int t0 = (wid & 1023) << 1;     // first of this wave's 2 rows
    const size_t bt0 = (size_t)b * T_ + t0;

    // ---- x loads: rows t0-1 .. t0+2, 2 float4 per lane per row (D=512)
    float4 xa[4][2];
    #pragma unroll
    for (int j = 0; j < 4; ++j) {
        const int u = t0 - 1 + j;
        if (u >= 0 && u < T_) {          // wave-uniform branch
            const float4* xr = (const float4*)(x + ((size_t)b * T_ + u) * D_);
            xa[j][0] = xr[lane];
            xa[j][1] = xr[lane + 64];
        } else {
            xa[j][0] = make_float4(0.f, 0.f, 0.f, 0.f);
            xa[j][1] = make_float4(0.f, 0.f, 0.f, 0.f);
        }
    }

    // ---- kern loads: 2 rows x 3 taps x 2 f4-slots = 12 float4 per lane.
    // Lane handles out float4-slots {lane, lane+64} of each row.
    float4 kk[2][3][2];
    #pragma unroll
    for (int r = 0; r < 2; ++r) {
        const float4* kr = (const float4*)(kern + (bt0 + r) * (size_t)(3 * F_));
        #pragma unroll
        for (int k = 0; k < 3; ++k) {
            kk[r][k][0] = kr[k * (F_ / 4) + lane];
            kk[r][k][1] = kr[k * (F_ / 4) + lane + 64];
        }
    }

    // ---- row sums S[j] = sum_d x[b, t0-1+j, :], butterfly -> all lanes
    float S[4];
    #pragma unroll
    for (int j = 0; j < 4; ++j) {
        const float4 a = xa[j][0], c = xa[j][1];
        float s = (a.x + a.y) + (a.z + a.w) + (c.x + c.y) + (c.z + c.w);
        #pragma unroll
        for (int off = 32; off > 0; off >>= 1)
            s += __shfl_xor(s, off, 64);
        S[j] = s;
    }

    // ---- 3-tap combine + store (coalesced: lanes 0..63 -> contiguous 16B)
    #pragma unroll
    for (int r = 0; r < 2; ++r) {
        float4* orow = (float4*)(out + (bt0 + r) * F_);
        const float s0 = S[r], s1 = S[r + 1], s2 = S[r + 2];
        #pragma unroll
        for (int h = 0; h < 2; ++h) {
            const float4 k0 = kk[r][0][h];
            const float4 k1 = kk[r][1][h];
            const float4 k2 = kk[r][2][h];
            float4 o;
            o.x = s0 * k0.x + s1 * k1.x + s2 * k2.x;
            o.y = s0 * k0.y + s1 * k1.y + s2 * k2.y;
            o.z = s0 * k0.z + s1 * k1.z + s2 * k2.z;
            o.w = s0 * k0.w + s1 * k1.w + s2 * k2.w;
            orow[lane + 64 * h] = o;
        }
    }
}

extern "C" void kernel_launch(void* const* d_in, const int* in_sizes, int n_in,
                              void* d_out, int out_size, void* d_ws, size_t ws_size,
                              hipStream_t stream) {
    const float* x    = (const float*)d_in[0];   // [B, T, D]
    const float* kern = (const float*)d_in[1];   // [B, T, K, F]
    float* out = (float*)d_out;                  // [B, T, F]
    (void)d_ws; (void)ws_size;

    // 16384 rows / 2 rows-per-wave / 4 waves-per-block = 2048 blocks
    fused_wave<<<(B_ * T_) / 8, 256, 0, stream>>>(x, kern, out);
}